// Round 10
// baseline (62.454 us; speedup 1.0000x reference)
//
#include <hip/hip_runtime.h>
#include <math.h>

// Problem constants
#define B_   4
#define N_   1024
#define K_   520
#define C2   128
#define NK   (N_*K_)
#define NROWS (B_*N_)                 // 4096
#define CNT1  ((float)(B_*N_*K_))     // 2129920
#define CNT2  ((float)(B_*N_))        // 4096
#define EPS_  1e-5f

// Workspace layout (float offsets).
#define OFF_PART1   0                          // [1024][32] moment partials
#define OFF_PART2   32768                      // [256][256] BN2 partials
#define OFF_M1      98304                      // [4096][64]  max_k h1
#define OFF_H2      360448                     // [4096][128] h2 (pre-BN2), [col][o]
#define OFF_W3T     884736                     // w3 as bf16 MFMA A-fragments (256 KB)
#define OFF_PSUM    1015808                    // [256][1024] per-tile h3 sums
#define OFF_PSQ     1277952                    // [256][1024]
#define OFF_PMAX    1540096                    // [256][1024]

typedef __attribute__((ext_vector_type(8))) short short8v;   // 8 bf16 (4 VGPR)
typedef __attribute__((ext_vector_type(4))) float f32x4;     // MFMA acc
typedef __attribute__((ext_vector_type(2))) float f32x2;     // packed fp32 (VOP3P)

__device__ __forceinline__ unsigned f2bf(float f) {          // RNE fp32->bf16
    unsigned u = __float_as_uint(f);
    unsigned r = u + 0x7FFFu + ((u >> 16) & 1u);
    return r >> 16;
}

// ---------------- K1: conv1 (6->64) + max over K + 27 moment partials -----------
// 1024 blocks x 256 thr; wave wv owns row bid*4+wv. Lane = k. Channel loop uses
// packed f32x2 (v_pk_fma_f32 / v_pk_max_f32): 4 sample-pairs + scalar j=8 tail.
__global__ __launch_bounds__(256) void k1_feat(const float* __restrict__ x,
                                               const float* __restrict__ ips,
                                               const float* __restrict__ w1,
                                               const float* __restrict__ b1,
                                               float* __restrict__ ws) {
    __shared__ __align__(16) float wts[64][4];     // wc0,wc1,wc2,b1
    __shared__ float wds[64][4];                   // wd0,wd1,wd2,pad
    __shared__ float base1s[4][64];
    __shared__ float lt[4][32][65];
    __shared__ float mom[4][28];
    float* m1    = ws + OFF_M1;
    float* part1 = ws + OFF_PART1;
    const int t = threadIdx.x;
    const int wv = t >> 6, lane = t & 63;
    const int row = blockIdx.x * 4 + wv;
    const int b = row >> 10, n = row & 1023;

    if (t < 64) {
        float w0 = w1[t*6+0], w1v = w1[t*6+1], w2v = w1[t*6+2];
        wts[t][0] = w0;  wts[t][1] = w1v;  wts[t][2] = w2v;  wts[t][3] = b1[t];
        wds[t][0] = w1[t*6+3]-w0;  wds[t][1] = w1[t*6+4]-w1v;
        wds[t][2] = w1[t*6+5]-w2v; wds[t][3] = 0.f;
    }
    __syncthreads();
    const float x0 = x[(b*3+0)*N_ + n];            // wave-uniform
    const float x1 = x[(b*3+1)*N_ + n];
    const float x2 = x[(b*3+2)*N_ + n];
    {   // base1 per channel (lane = c)
        const float* wd = wds[lane];
        base1s[wv][lane] = fmaf(wd[0], x0, fmaf(wd[1], x1, fmaf(wd[2], x2, wts[lane][3])));
    }
    const size_t gb = ((size_t)(b*3)*N_ + n) * (size_t)K_;
    float a0[9], a1[9], a2[9];
    #pragma unroll
    for (int j = 0; j < 8; ++j) {
        a0[j] = ips[gb        + j*64 + lane];
        a1[j] = ips[gb +   NK + j*64 + lane];
        a2[j] = ips[gb + 2*NK + j*64 + lane];
    }
    const bool extra = (lane < 8);
    {
        int keo = extra ? (512 + lane) : lane;
        float v0 = ips[gb + keo], v1 = ips[gb + NK + keo], v2 = ips[gb + 2*NK + keo];
        a0[8] = extra ? v0 : 0.f;  a1[8] = extra ? v1 : 0.f;  a2[8] = extra ? v2 : 0.f;
    }
    // pack j=0..7 into f32x2 pairs for VOP3P
    f32x2 A0[4], A1[4], A2[4];
    #pragma unroll
    for (int p = 0; p < 4; ++p) {
        A0[p] = (f32x2){a0[2*p], a0[2*p+1]};
        A1[p] = (f32x2){a1[2*p], a1[2*p+1]};
        A2[p] = (f32x2){a2[2*p], a2[2*p+1]};
    }
    // per-channel max over K, two batches of 32 channels via LDS transpose
    float m_out0 = 0.f, m_out1 = 0.f;
    #pragma unroll
    for (int cb = 0; cb < 2; ++cb) {
        #pragma unroll 8
        for (int ci = 0; ci < 32; ++ci) {
            const int c = cb*32 + ci;
            const float4 wt = *(const float4*)wts[c];      // broadcast b128
            const float bs = base1s[wv][c];                // broadcast b32
            const f32x2 wx = {wt.x, wt.x}, wy = {wt.y, wt.y}, wz = {wt.z, wt.z};
            const f32x2 bs2 = {bs, bs};
            f32x2 vm2 = {-INFINITY, -INFINITY};
            #pragma unroll
            for (int p = 0; p < 4; ++p) {
                f32x2 h = wx*A0[p] + wy*A1[p] + wz*A2[p] + bs2;  // pk_fma chain
                vm2 = __builtin_elementwise_max(vm2, h);          // pk_max
            }
            float vm = fmaxf(vm2.x, vm2.y);
            float h8 = fmaf(wt.x, a0[8], fmaf(wt.y, a1[8], fmaf(wt.z, a2[8], bs)));
            float vmE = fmaxf(vm, h8);
            vm = extra ? vmE : vm;                         // pad lanes exclude j=8
            lt[wv][ci][lane] = vm;                         // conflict-free write
        }
        const int ci = lane & 31, half = lane >> 5;
        float p = -INFINITY;
        #pragma unroll
        for (int j = 0; j < 32; ++j) p = fmaxf(p, lt[wv][ci][half*32 + j]);
        p = fmaxf(p, __shfl_xor(p, 32));
        if (cb == 0) m_out0 = p; else m_out1 = p;
    }
    if (lane < 32) {
        m1[(size_t)row*64 + lane]      = m_out0;
        m1[(size_t)row*64 + 32 + lane] = m_out1;
    }
    // moments from the same registers
    float mg0=0,mg1=0,mg2=0,mg3=0,mg4=0,mg5=0,s0=0,s1=0,s2=0;
    #pragma unroll
    for (int j = 0; j < 9; ++j) {
        float i0=a0[j], i1=a1[j], i2=a2[j];
        mg0=fmaf(i0,i0,mg0); mg1=fmaf(i0,i1,mg1); mg2=fmaf(i0,i2,mg2);
        mg3=fmaf(i1,i1,mg3); mg4=fmaf(i1,i2,mg4); mg5=fmaf(i2,i2,mg5);
        s0+=i0; s1+=i1; s2+=i2;
    }
    #pragma unroll
    for (int off=32; off>0; off>>=1) {
        mg0+=__shfl_xor(mg0,off); mg1+=__shfl_xor(mg1,off); mg2+=__shfl_xor(mg2,off);
        mg3+=__shfl_xor(mg3,off); mg4+=__shfl_xor(mg4,off); mg5+=__shfl_xor(mg5,off);
        s0 +=__shfl_xor(s0, off); s1 +=__shfl_xor(s1, off); s2 +=__shfl_xor(s2, off);
    }
    if (lane == 0) {
        float* mo = mom[wv];
        mo[0]=mg0; mo[1]=mg1; mo[2]=mg2; mo[3]=mg3; mo[4]=mg4; mo[5]=mg5;
        mo[6]=s0;  mo[7]=s1;  mo[8]=s2;
        mo[9] =s0*x0; mo[10]=s0*x1; mo[11]=s0*x2;
        mo[12]=s1*x0; mo[13]=s1*x1; mo[14]=s1*x2;
        mo[15]=s2*x0; mo[16]=s2*x1; mo[17]=s2*x2;
        mo[18]=x0*x0; mo[19]=x0*x1; mo[20]=x0*x2; mo[21]=x1*x1; mo[22]=x1*x2; mo[23]=x2*x2;
        mo[24]=x0; mo[25]=x1; mo[26]=x2;
    }
    __syncthreads();
    if (t < 32)   // zero-pad slots 27..31 so K2's float4 reduce is poison-free
        part1[blockIdx.x*32 + t] =
            (t < 27) ? (mom[0][t] + mom[1][t] + mom[2][t] + mom[3][t]) : 0.f;
}

// ---------------- K2': BN1 reduce + w3 bf16-fragment pack + FC2 + BN2 partials --
// 256 blocks x 256 thr, 16 cols each. BN1 moment reduce now fully-coalesced
// float4: thread t owns slot-group t&7, rows (t>>3)+32*it, 32 iterations.
__global__ __launch_bounds__(256) void k2_fc2(const float* __restrict__ w1,
                                              const float* __restrict__ b1,
                                              const float* __restrict__ g1,
                                              const float* __restrict__ be1,
                                              const float* __restrict__ w2,
                                              const float* __restrict__ b2,
                                              const float* __restrict__ w3,
                                              float* __restrict__ ws) {
    __shared__ float w2l[C2 * 65];
    __shared__ __align__(16) float red4[32][8][4];
    __shared__ float mo[32];
    __shared__ float sc1[64], sh1[64];
    __shared__ float r1c[128];
    __shared__ float lred[256];
    const int t = threadIdx.x;
    const int bid = blockIdx.x;
    const float* m1 = ws + OFF_M1;
    float* h2    = ws + OFF_H2;
    float* part2 = ws + OFF_PART2;
    if (bid < 64) {   // w3 -> bf16 A-fragments (16384 slots x 16B)
        const int slot = bid*256 + t;
        const int Mb = slot >> 8, s = (slot >> 6) & 3, l2 = slot & 63;
        const int row = l2 & 15, g = l2 >> 4;
        const float* src = w3 + (size_t)(Mb*16 + row)*128 + s*32 + g*8;
        float4 f0 = *(const float4*)src;
        float4 f1 = *(const float4*)(src + 4);
        uint4 u;
        u.x = f2bf(f0.x) | (f2bf(f0.y) << 16);
        u.y = f2bf(f0.z) | (f2bf(f0.w) << 16);
        u.z = f2bf(f1.x) | (f2bf(f1.y) << 16);
        u.w = f2bf(f1.z) | (f2bf(f1.w) << 16);
        ((uint4*)(ws + OFF_W3T))[slot] = u;
    }
    {   // BN1 moment reduce, coalesced float4 (deterministic fixed order)
        const float4* p14 = (const float4*)(ws + OFF_PART1);   // [1024][8] float4
        const int sg = t & 7, rr = t >> 3;
        float4 acc = {0.f, 0.f, 0.f, 0.f};
        #pragma unroll 4
        for (int it = 0; it < 32; ++it) {
            float4 v = p14[(size_t)(rr + 32*it)*8 + sg];
            acc.x += v.x; acc.y += v.y; acc.z += v.z; acc.w += v.w;
        }
        *(float4*)&red4[rr][sg][0] = acc;
    }
    for (int idx = t; idx < C2 * 64; idx += 256) {  // stage w2 (padded rows)
        int o = idx >> 6, i = idx & 63;
        w2l[o * 65 + i] = w2[idx];
    }
    __syncthreads();
    if (t < 32) {
        float m = 0.f;
        #pragma unroll
        for (int k = 0; k < 32; ++k) m += red4[k][t >> 2][t & 3];
        mo[t] = m;
    }
    __syncthreads();
    if (t < 64) {   // BN1 closed form (proven R4)
        const int c = t;
        float w0 = w1[c*6+0], w1v = w1[c*6+1], w2v = w1[c*6+2];
        float wd0 = w1[c*6+3]-w0, wd1 = w1[c*6+4]-w1v, wd2 = w1[c*6+5]-w2v;
        float bb = b1[c];
        float wcS = w0*mo[6] + w1v*mo[7] + w2v*mo[8];
        float wdX = wd0*mo[24] + wd1*mo[25] + wd2*mo[26];
        float ssum = wcS + 520.f*(wdX + 4096.f*bb);
        float t1 = w0*w0*mo[0] + w1v*w1v*mo[3] + w2v*w2v*mo[5]
                 + 2.f*(w0*w1v*mo[1] + w0*w2v*mo[2] + w1v*w2v*mo[4]);
        float Pt = w0 *(mo[9]*wd0  + mo[10]*wd1 + mo[11]*wd2)
                 + w1v*(mo[12]*wd0 + mo[13]*wd1 + mo[14]*wd2)
                 + w2v*(mo[15]*wd0 + mo[16]*wd1 + mo[17]*wd2);
        float t2 = 2.f*(Pt + bb*wcS);
        float Qt = wd0*wd0*mo[18] + wd1*wd1*mo[21] + wd2*wd2*mo[23]
                 + 2.f*(wd0*wd1*mo[19] + wd0*wd2*mo[20] + wd1*wd2*mo[22]);
        float t3 = 520.f*(Qt + 2.f*bb*wdX + 4096.f*bb*bb);
        float mean = ssum * (1.f / CNT1);
        float var  = (t1+t2+t3) * (1.f / CNT1) - mean*mean;
        float sc   = g1[c] * rsqrtf(var + EPS_);
        sc1[c] = sc;
        sh1[c] = fmaf(-mean, sc, be1[c]);
    }
    const int o = t & 127, cg = t >> 7;
    const float bo = b2[o];
    float s2 = 0.f, q2 = 0.f;
    const int colbase = bid * 16;
    __syncthreads();
    for (int it = 0; it < 8; ++it) {
        __syncthreads();                            // protect r1c reuse
        if (t < 128) {
            int ci = t & 63, g = t >> 6;
            float v = m1[(size_t)(colbase + it * 2 + g) * 64 + ci];
            r1c[t] = fmaxf(0.f, fmaf(v, sc1[ci], sh1[ci]));
        }
        __syncthreads();
        float acc = 0.f;
        const float* wr = w2l + o * 65;
        const float* rr = r1c + cg * 64;
        #pragma unroll 8
        for (int i = 0; i < 64; ++i) acc = fmaf(wr[i], rr[i], acc);
        float h = acc + bo;
        h2[(size_t)(colbase + it * 2 + cg) * 128 + o] = h;   // [col][o], coalesced
        s2 += h;
        q2 = fmaf(h, h, q2);
    }
    __syncthreads();
    lred[t] = s2;
    __syncthreads();
    if (t < 128) part2[bid * 256 + t] = lred[t] + lred[128 + t];
    __syncthreads();
    lred[t] = q2;
    __syncthreads();
    if (t < 128) part2[bid * 256 + 128 + t] = lred[t] + lred[128 + t];
}

// ---------------- K3': BN2 reduce + FC3 via bf16 MFMA + h3 tile partials --------
// (R9, passing.) 256 blocks x 512 thr (8 waves). Tile = 16 cols of one b.
__global__ __launch_bounds__(512) void k3_fc3(const float* __restrict__ g2,
                                              const float* __restrict__ be2,
                                              const float* __restrict__ b3,
                                              float* __restrict__ ws) {
    __shared__ float tot2[2][256];
    __shared__ float sc2[128], sh2[128];
    __shared__ __align__(16) unsigned short r2c[16 * 136];   // bf16 B, padded rows
    __shared__ float dstg[8][16][20];                        // per-wave D transpose
    const int t = threadIdx.x;
    const int w = t >> 6, l = t & 63;
    const float* h2  = ws + OFF_H2;
    float* psum = ws + OFF_PSUM;
    float* psq  = ws + OFF_PSQ;
    float* pmax = ws + OFF_PMAX;
    const int tile = blockIdx.x;                    // 0..255
    const int b = tile >> 6, n0 = (tile & 63) * 16;
    {   // BN2 reduce (redundant per block; deterministic fixed order)
        const float* part2 = ws + OFF_PART2;
        const int c2 = t & 255, h = t >> 8;
        float acc = 0.f;
        for (int r = 0; r < 128; ++r) acc += part2[(h*128 + r)*256 + c2];
        tot2[h][c2] = acc;
    }
    __syncthreads();
    if (t < 128) {
        float s = tot2[0][t]       + tot2[1][t];
        float q = tot2[0][128 + t] + tot2[1][128 + t];
        float mean = s * (1.f / CNT2);
        float var  = q * (1.f / CNT2) - mean*mean;
        float sc   = g2[t] * rsqrtf(var + EPS_);
        sc2[t] = sc;
        sh2[t] = fmaf(-mean, sc, be2[t]);
    }
    __syncthreads();
    {   // stage r2 tile as bf16: r2c[col][k], col = n-index, k = input channel
        const int col = t >> 5, k0 = (t & 31) * 4;
        float4 v = *(const float4*)(h2 + (size_t)(b * N_ + n0 + col) * 128 + k0);
        float r0 = fmaxf(0.f, fmaf(v.x, sc2[k0+0], sh2[k0+0]));
        float r1 = fmaxf(0.f, fmaf(v.y, sc2[k0+1], sh2[k0+1]));
        float r2 = fmaxf(0.f, fmaf(v.z, sc2[k0+2], sh2[k0+2]));
        float r3 = fmaxf(0.f, fmaf(v.w, sc2[k0+3], sh2[k0+3]));
        unsigned u0 = f2bf(r0) | (f2bf(r1) << 16);
        unsigned u1 = f2bf(r2) | (f2bf(r3) << 16);
        *(uint2*)&r2c[col * 136 + k0] = make_uint2(u0, u1);
    }
    __syncthreads();
    // B fragments: lane l -> col = l&15, k = s*32 + (l>>4)*8 + j
    short8v bfrag[4];
    {
        const int bc = (l & 15) * 136 + (l >> 4) * 8;
        #pragma unroll
        for (int s = 0; s < 4; ++s)
            bfrag[s] = *(const short8v*)&r2c[bc + s * 32];
    }
    // 32 MFMA per wave: 8 m-blocks x 4 k-steps, A streamed from L2
    const short8v* w3mf = (const short8v*)(ws + OFF_W3T);
    f32x4 acc[8];
    #pragma unroll
    for (int m = 0; m < 8; ++m) {
        f32x4 a = {0.f, 0.f, 0.f, 0.f};
        const int Mb = w * 8 + m;
        #pragma unroll
        for (int s = 0; s < 4; ++s) {
            short8v av = w3mf[(Mb * 4 + s) * 64 + l];
            a = __builtin_amdgcn_mfma_f32_16x16x32_bf16(av, bfrag[s], a, 0, 0, 0);
        }
        acc[m] = a;
    }
    // per-m: transpose D through per-wave LDS, reduce 16 cols per channel
    for (int m = 0; m < 8; ++m) {
        #pragma unroll
        for (int r = 0; r < 4; ++r)
            dstg[w][(l >> 4) * 4 + r][l & 15] = acc[m][r];
        __syncthreads();                            // uniform; also compiler fence
        const int row = l & 15, cg = l >> 4;
        float4 d4 = *(const float4*)&dstg[w][row][cg * 4];
        float bv = b3[w * 128 + m * 16 + row];
        float v0 = d4.x + bv, v1 = d4.y + bv, v2 = d4.z + bv, v3 = d4.w + bv;
        float s4 = (v0 + v1) + (v2 + v3);
        float q4 = fmaf(v0, v0, fmaf(v1, v1, fmaf(v2, v2, v3 * v3)));
        float m4 = fmaxf(fmaxf(v0, v1), fmaxf(v2, v3));
        s4 += __shfl_xor(s4, 16); q4 += __shfl_xor(q4, 16); m4 = fmaxf(m4, __shfl_xor(m4, 16));
        s4 += __shfl_xor(s4, 32); q4 += __shfl_xor(q4, 32); m4 = fmaxf(m4, __shfl_xor(m4, 32));
        __syncthreads();                            // drain reads before next m's writes
        if (l < 16) {
            const size_t o6 = (size_t)tile * 1024 + w * 128 + m * 16 + l;
            psum[o6] = s4;  psq[o6] = q4;  pmax[o6] = m4;
        }
    }
}

// ---------------- K4': BN3 stats + max over n + output (passing) ----------------
__global__ __launch_bounds__(256) void k4_out(const float* __restrict__ g3,
                                              const float* __restrict__ be3,
                                              float* __restrict__ out,
                                              const float* __restrict__ ws) {
    __shared__ float lsum[256], lsq[256], lmax[256];
    const int t = threadIdx.x;
    const int c = blockIdx.x;
    const float* psum = ws + OFF_PSUM;
    const float* psq  = ws + OFF_PSQ;
    const float* pmax = ws + OFF_PMAX;
    lsum[t] = psum[(size_t)t * 1024 + c];
    lsq[t]  = psq [(size_t)t * 1024 + c];
    lmax[t] = pmax[(size_t)t * 1024 + c];
    __syncthreads();
    for (int s = 128; s > 0; s >>= 1) {
        if (t < s) { lsum[t] += lsum[t + s]; lsq[t] += lsq[t + s]; }
        __syncthreads();
    }
    float mean = lsum[0] * (1.f / CNT2);
    float var  = lsq[0] * (1.f / CNT2) - mean * mean;
    float rs   = rsqrtf(var + EPS_);
    float sc   = g3[c] * rs;
    float sh   = fmaf(-mean, sc, be3[c]);
    const int wv = t >> 6, l = t & 63;
    float v = lmax[wv * 64 + l];                    // tile = wv*64+l is batch wv
    #pragma unroll
    for (int off = 32; off > 0; off >>= 1) v = fmaxf(v, __shfl_xor(v, off));
    if (l == 0) out[wv * 1024 + c] = fmaf(v, sc, sh);
}

extern "C" void kernel_launch(void* const* d_in, const int* in_sizes, int n_in,
                              void* d_out, int out_size, void* d_ws, size_t ws_size,
                              hipStream_t stream) {
    const float* x   = (const float*)d_in[0];
    const float* ips = (const float*)d_in[1];
    const float* w1  = (const float*)d_in[2];
    const float* b1  = (const float*)d_in[3];
    const float* g1  = (const float*)d_in[4];
    const float* be1 = (const float*)d_in[5];
    const float* w2  = (const float*)d_in[6];
    const float* b2  = (const float*)d_in[7];
    const float* g2  = (const float*)d_in[8];
    const float* be2 = (const float*)d_in[9];
    const float* w3  = (const float*)d_in[10];
    const float* b3  = (const float*)d_in[11];
    const float* g3  = (const float*)d_in[12];
    const float* be3 = (const float*)d_in[13];
    float* out = (float*)d_out;
    float* ws  = (float*)d_ws;

    hipLaunchKernelGGL(k1_feat, dim3(1024), dim3(256), 0, stream, x, ips, w1, b1, ws);
    hipLaunchKernelGGL(k2_fc2,  dim3(256),  dim3(256), 0, stream, w1, b1, g1, be1, w2, b2, w3, ws);
    hipLaunchKernelGGL(k3_fc3,  dim3(256),  dim3(512), 0, stream, g2, be2, b3, ws);
    hipLaunchKernelGGL(k4_out,  dim3(1024), dim3(256), 0, stream, g3, be3, out, ws);
}

// Round 11
// 59.562 us; speedup vs baseline: 1.0486x; 1.0486x over previous
//
#include <hip/hip_runtime.h>
#include <math.h>

// Problem constants
#define B_   4
#define N_   1024
#define K_   520
#define C2   128
#define NK   (N_*K_)
#define NROWS (B_*N_)                 // 4096
#define CNT1  ((float)(B_*N_*K_))     // 2129920
#define CNT2  ((float)(B_*N_))        // 4096
#define EPS_  1e-5f

// Workspace layout (float offsets).
#define OFF_PART1   0                          // [1024][32] moment partials
#define OFF_PART2   32768                      // [256][256] BN2 partials
#define OFF_M1      98304                      // [4096][64]  max_k h1
#define OFF_H2      360448                     // [4096][128] h2 (pre-BN2), [col][o]
#define OFF_W3T     884736                     // w3 as bf16 MFMA A-fragments (256 KB)
#define OFF_PSUM    1015808                    // [256][1024] per-tile h3 sums
#define OFF_PSQ     1277952                    // [256][1024]
#define OFF_PMAX    1540096                    // [256][1024]

typedef __attribute__((ext_vector_type(8))) short short8v;   // 8 bf16 (4 VGPR)
typedef __attribute__((ext_vector_type(4))) float f32x4;     // MFMA acc
typedef __attribute__((ext_vector_type(2))) float f32x2;     // packed fp32 (VOP3P)

__device__ __forceinline__ unsigned f2bf(float f) {          // RNE fp32->bf16
    unsigned u = __float_as_uint(f);
    unsigned r = u + 0x7FFFu + ((u >> 16) & 1u);
    return r >> 16;
}

// ---------------- K1: conv1 (6->64) + max over K + 27 moment partials -----------
// 1024 blocks x 256 thr; wave wv owns row bid*4+wv. Lane = k.
// DS-diet vs R10: channel weights are read as UNIFORM global loads (scalar pipe)
// instead of LDS b128 broadcasts — the DS pipe (per-CU, 16 waves contending) was
// the bottleneck; only base1s (b32) + lt transpose + shfls remain on DS.
__global__ __launch_bounds__(256) void k1_feat(const float* __restrict__ x,
                                               const float* __restrict__ ips,
                                               const float* __restrict__ w1,
                                               const float* __restrict__ b1,
                                               float* __restrict__ ws) {
    __shared__ float base1s[4][64];
    __shared__ float lt[4][32][65];
    __shared__ float mom[4][28];
    float* m1    = ws + OFF_M1;
    float* part1 = ws + OFF_PART1;
    const int t = threadIdx.x;
    const int wv = t >> 6, lane = t & 63;
    const int row = blockIdx.x * 4 + wv;
    const int b = row >> 10, n = row & 1023;

    const float x0 = x[(b*3+0)*N_ + n];            // wave-uniform
    const float x1 = x[(b*3+1)*N_ + n];
    const float x2 = x[(b*3+2)*N_ + n];
    {   // base1 per channel (lane = c): per-lane loads, 3 fma, one LDS write
        const int c = lane;
        float wd0 = w1[c*6+3] - w1[c*6+0];
        float wd1 = w1[c*6+4] - w1[c*6+1];
        float wd2 = w1[c*6+5] - w1[c*6+2];
        base1s[wv][c] = fmaf(wd0, x0, fmaf(wd1, x1, fmaf(wd2, x2, b1[c])));
    }
    const size_t gb = ((size_t)(b*3)*N_ + n) * (size_t)K_;
    float a0[9], a1[9], a2[9];
    #pragma unroll
    for (int j = 0; j < 8; ++j) {
        a0[j] = ips[gb        + j*64 + lane];
        a1[j] = ips[gb +   NK + j*64 + lane];
        a2[j] = ips[gb + 2*NK + j*64 + lane];
    }
    const bool extra = (lane < 8);
    {
        int keo = extra ? (512 + lane) : lane;
        float v0 = ips[gb + keo], v1 = ips[gb + NK + keo], v2 = ips[gb + 2*NK + keo];
        a0[8] = extra ? v0 : 0.f;  a1[8] = extra ? v1 : 0.f;  a2[8] = extra ? v2 : 0.f;
    }
    // pack j=0..7 into f32x2 pairs for VOP3P
    f32x2 A0[4], A1[4], A2[4];
    #pragma unroll
    for (int p = 0; p < 4; ++p) {
        A0[p] = (f32x2){a0[2*p], a0[2*p+1]};
        A1[p] = (f32x2){a1[2*p], a1[2*p+1]};
        A2[p] = (f32x2){a2[2*p], a2[2*p+1]};
    }
    // per-channel max over K, two batches of 32 channels via LDS transpose.
    // lt[wv] is wave-private: DS ops are in-order per wave, no barriers needed.
    float m_out0 = 0.f, m_out1 = 0.f;
    #pragma unroll
    for (int cb = 0; cb < 2; ++cb) {
        #pragma unroll 8
        for (int ci = 0; ci < 32; ++ci) {
            const int c = cb*32 + ci;
            const float wc0 = w1[c*6+0];           // uniform -> scalar loads
            const float wc1 = w1[c*6+1];
            const float wc2 = w1[c*6+2];
            const float bs = base1s[wv][c];        // broadcast b32
            const f32x2 wx = {wc0, wc0}, wy = {wc1, wc1}, wz = {wc2, wc2};
            const f32x2 bs2 = {bs, bs};
            f32x2 vm2 = {-INFINITY, -INFINITY};
            #pragma unroll
            for (int p = 0; p < 4; ++p) {
                f32x2 h = wx*A0[p] + wy*A1[p] + wz*A2[p] + bs2;  // pk_fma chain
                vm2 = __builtin_elementwise_max(vm2, h);          // pk_max
            }
            float vm = fmaxf(vm2.x, vm2.y);
            float h8 = fmaf(wc0, a0[8], fmaf(wc1, a1[8], fmaf(wc2, a2[8], bs)));
            float vmE = fmaxf(vm, h8);
            vm = extra ? vmE : vm;                 // pad lanes exclude j=8
            lt[wv][ci][lane] = vm;                 // conflict-free write
        }
        const int ci = lane & 31, half = lane >> 5;
        float p = -INFINITY;
        #pragma unroll
        for (int j = 0; j < 32; ++j) p = fmaxf(p, lt[wv][ci][half*32 + j]);
        p = fmaxf(p, __shfl_xor(p, 32));
        if (cb == 0) m_out0 = p; else m_out1 = p;
    }
    if (lane < 32) {
        m1[(size_t)row*64 + lane]      = m_out0;
        m1[(size_t)row*64 + 32 + lane] = m_out1;
    }
    // moments from the same registers
    float mg0=0,mg1=0,mg2=0,mg3=0,mg4=0,mg5=0,s0=0,s1=0,s2=0;
    #pragma unroll
    for (int j = 0; j < 9; ++j) {
        float i0=a0[j], i1=a1[j], i2=a2[j];
        mg0=fmaf(i0,i0,mg0); mg1=fmaf(i0,i1,mg1); mg2=fmaf(i0,i2,mg2);
        mg3=fmaf(i1,i1,mg3); mg4=fmaf(i1,i2,mg4); mg5=fmaf(i2,i2,mg5);
        s0+=i0; s1+=i1; s2+=i2;
    }
    #pragma unroll
    for (int off=32; off>0; off>>=1) {
        mg0+=__shfl_xor(mg0,off); mg1+=__shfl_xor(mg1,off); mg2+=__shfl_xor(mg2,off);
        mg3+=__shfl_xor(mg3,off); mg4+=__shfl_xor(mg4,off); mg5+=__shfl_xor(mg5,off);
        s0 +=__shfl_xor(s0, off); s1 +=__shfl_xor(s1, off); s2 +=__shfl_xor(s2, off);
    }
    if (lane == 0) {
        float* mo = mom[wv];
        mo[0]=mg0; mo[1]=mg1; mo[2]=mg2; mo[3]=mg3; mo[4]=mg4; mo[5]=mg5;
        mo[6]=s0;  mo[7]=s1;  mo[8]=s2;
        mo[9] =s0*x0; mo[10]=s0*x1; mo[11]=s0*x2;
        mo[12]=s1*x0; mo[13]=s1*x1; mo[14]=s1*x2;
        mo[15]=s2*x0; mo[16]=s2*x1; mo[17]=s2*x2;
        mo[18]=x0*x0; mo[19]=x0*x1; mo[20]=x0*x2; mo[21]=x1*x1; mo[22]=x1*x2; mo[23]=x2*x2;
        mo[24]=x0; mo[25]=x1; mo[26]=x2;
    }
    __syncthreads();
    if (t < 32)   // zero-pad slots 27..31 so K2's float4 reduce is poison-free
        part1[blockIdx.x*32 + t] =
            (t < 27) ? (mom[0][t] + mom[1][t] + mom[2][t] + mom[3][t]) : 0.f;
}

// ---------------- K2': BN1 reduce + w3 bf16-fragment pack + FC2 + BN2 partials --
// (R10, passing.) 256 blocks x 256 thr, 16 cols each.
__global__ __launch_bounds__(256) void k2_fc2(const float* __restrict__ w1,
                                              const float* __restrict__ b1,
                                              const float* __restrict__ g1,
                                              const float* __restrict__ be1,
                                              const float* __restrict__ w2,
                                              const float* __restrict__ b2,
                                              const float* __restrict__ w3,
                                              float* __restrict__ ws) {
    __shared__ float w2l[C2 * 65];
    __shared__ __align__(16) float red4[32][8][4];
    __shared__ float mo[32];
    __shared__ float sc1[64], sh1[64];
    __shared__ float r1c[128];
    __shared__ float lred[256];
    const int t = threadIdx.x;
    const int bid = blockIdx.x;
    const float* m1 = ws + OFF_M1;
    float* h2    = ws + OFF_H2;
    float* part2 = ws + OFF_PART2;
    if (bid < 64) {   // w3 -> bf16 A-fragments (16384 slots x 16B)
        const int slot = bid*256 + t;
        const int Mb = slot >> 8, s = (slot >> 6) & 3, l2 = slot & 63;
        const int row = l2 & 15, g = l2 >> 4;
        const float* src = w3 + (size_t)(Mb*16 + row)*128 + s*32 + g*8;
        float4 f0 = *(const float4*)src;
        float4 f1 = *(const float4*)(src + 4);
        uint4 u;
        u.x = f2bf(f0.x) | (f2bf(f0.y) << 16);
        u.y = f2bf(f0.z) | (f2bf(f0.w) << 16);
        u.z = f2bf(f1.x) | (f2bf(f1.y) << 16);
        u.w = f2bf(f1.z) | (f2bf(f1.w) << 16);
        ((uint4*)(ws + OFF_W3T))[slot] = u;
    }
    {   // BN1 moment reduce, coalesced float4 (deterministic fixed order)
        const float4* p14 = (const float4*)(ws + OFF_PART1);   // [1024][8] float4
        const int sg = t & 7, rr = t >> 3;
        float4 acc = {0.f, 0.f, 0.f, 0.f};
        #pragma unroll 4
        for (int it = 0; it < 32; ++it) {
            float4 v = p14[(size_t)(rr + 32*it)*8 + sg];
            acc.x += v.x; acc.y += v.y; acc.z += v.z; acc.w += v.w;
        }
        *(float4*)&red4[rr][sg][0] = acc;
    }
    for (int idx = t; idx < C2 * 64; idx += 256) {  // stage w2 (padded rows)
        int o = idx >> 6, i = idx & 63;
        w2l[o * 65 + i] = w2[idx];
    }
    __syncthreads();
    if (t < 32) {
        float m = 0.f;
        #pragma unroll
        for (int k = 0; k < 32; ++k) m += red4[k][t >> 2][t & 3];
        mo[t] = m;
    }
    __syncthreads();
    if (t < 64) {   // BN1 closed form (proven R4)
        const int c = t;
        float w0 = w1[c*6+0], w1v = w1[c*6+1], w2v = w1[c*6+2];
        float wd0 = w1[c*6+3]-w0, wd1 = w1[c*6+4]-w1v, wd2 = w1[c*6+5]-w2v;
        float bb = b1[c];
        float wcS = w0*mo[6] + w1v*mo[7] + w2v*mo[8];
        float wdX = wd0*mo[24] + wd1*mo[25] + wd2*mo[26];
        float ssum = wcS + 520.f*(wdX + 4096.f*bb);
        float t1 = w0*w0*mo[0] + w1v*w1v*mo[3] + w2v*w2v*mo[5]
                 + 2.f*(w0*w1v*mo[1] + w0*w2v*mo[2] + w1v*w2v*mo[4]);
        float Pt = w0 *(mo[9]*wd0  + mo[10]*wd1 + mo[11]*wd2)
                 + w1v*(mo[12]*wd0 + mo[13]*wd1 + mo[14]*wd2)
                 + w2v*(mo[15]*wd0 + mo[16]*wd1 + mo[17]*wd2);
        float t2 = 2.f*(Pt + bb*wcS);
        float Qt = wd0*wd0*mo[18] + wd1*wd1*mo[21] + wd2*wd2*mo[23]
                 + 2.f*(wd0*wd1*mo[19] + wd0*wd2*mo[20] + wd1*wd2*mo[22]);
        float t3 = 520.f*(Qt + 2.f*bb*wdX + 4096.f*bb*bb);
        float mean = ssum * (1.f / CNT1);
        float var  = (t1+t2+t3) * (1.f / CNT1) - mean*mean;
        float sc   = g1[c] * rsqrtf(var + EPS_);
        sc1[c] = sc;
        sh1[c] = fmaf(-mean, sc, be1[c]);
    }
    const int o = t & 127, cg = t >> 7;
    const float bo = b2[o];
    float s2 = 0.f, q2 = 0.f;
    const int colbase = bid * 16;
    __syncthreads();
    for (int it = 0; it < 8; ++it) {
        __syncthreads();                            // protect r1c reuse
        if (t < 128) {
            int ci = t & 63, g = t >> 6;
            float v = m1[(size_t)(colbase + it * 2 + g) * 64 + ci];
            r1c[t] = fmaxf(0.f, fmaf(v, sc1[ci], sh1[ci]));
        }
        __syncthreads();
        float acc = 0.f;
        const float* wr = w2l + o * 65;
        const float* rr = r1c + cg * 64;
        #pragma unroll 8
        for (int i = 0; i < 64; ++i) acc = fmaf(wr[i], rr[i], acc);
        float h = acc + bo;
        h2[(size_t)(colbase + it * 2 + cg) * 128 + o] = h;   // [col][o], coalesced
        s2 += h;
        q2 = fmaf(h, h, q2);
    }
    __syncthreads();
    lred[t] = s2;
    __syncthreads();
    if (t < 128) part2[bid * 256 + t] = lred[t] + lred[128 + t];
    __syncthreads();
    lred[t] = q2;
    __syncthreads();
    if (t < 128) part2[bid * 256 + 128 + t] = lred[t] + lred[128 + t];
}

// ---------------- K3': BN2 reduce + FC3 via bf16 MFMA + h3 tile partials --------
// 256 blocks x 512 thr (8 waves). Tile = 16 cols of one b. dstg is wave-private
// and DS ops are in-order per wave -> NO barriers in the per-m epilogue loop.
__global__ __launch_bounds__(512) void k3_fc3(const float* __restrict__ g2,
                                              const float* __restrict__ be2,
                                              const float* __restrict__ b3,
                                              float* __restrict__ ws) {
    __shared__ float tot2[2][256];
    __shared__ float sc2[128], sh2[128];
    __shared__ __align__(16) unsigned short r2c[16 * 136];   // bf16 B, padded rows
    __shared__ float dstg[8][16][20];                        // per-wave D transpose
    const int t = threadIdx.x;
    const int w = t >> 6, l = t & 63;
    const float* h2  = ws + OFF_H2;
    float* psum = ws + OFF_PSUM;
    float* psq  = ws + OFF_PSQ;
    float* pmax = ws + OFF_PMAX;
    const int tile = blockIdx.x;                    // 0..255
    const int b = tile >> 6, n0 = (tile & 63) * 16;
    {   // BN2 reduce (redundant per block; deterministic fixed order)
        const float* part2 = ws + OFF_PART2;
        const int c2 = t & 255, h = t >> 8;
        float acc = 0.f;
        for (int r = 0; r < 128; ++r) acc += part2[(h*128 + r)*256 + c2];
        tot2[h][c2] = acc;
    }
    __syncthreads();
    if (t < 128) {
        float s = tot2[0][t]       + tot2[1][t];
        float q = tot2[0][128 + t] + tot2[1][128 + t];
        float mean = s * (1.f / CNT2);
        float var  = q * (1.f / CNT2) - mean*mean;
        float sc   = g2[t] * rsqrtf(var + EPS_);
        sc2[t] = sc;
        sh2[t] = fmaf(-mean, sc, be2[t]);
    }
    __syncthreads();
    {   // stage r2 tile as bf16: r2c[col][k], col = n-index, k = input channel
        const int col = t >> 5, k0 = (t & 31) * 4;
        float4 v = *(const float4*)(h2 + (size_t)(b * N_ + n0 + col) * 128 + k0);
        float r0 = fmaxf(0.f, fmaf(v.x, sc2[k0+0], sh2[k0+0]));
        float r1 = fmaxf(0.f, fmaf(v.y, sc2[k0+1], sh2[k0+1]));
        float r2 = fmaxf(0.f, fmaf(v.z, sc2[k0+2], sh2[k0+2]));
        float r3 = fmaxf(0.f, fmaf(v.w, sc2[k0+3], sh2[k0+3]));
        unsigned u0 = f2bf(r0) | (f2bf(r1) << 16);
        unsigned u1 = f2bf(r2) | (f2bf(r3) << 16);
        *(uint2*)&r2c[col * 136 + k0] = make_uint2(u0, u1);
    }
    __syncthreads();
    // B fragments: lane l -> col = l&15, k = s*32 + (l>>4)*8 + j
    short8v bfrag[4];
    {
        const int bc = (l & 15) * 136 + (l >> 4) * 8;
        #pragma unroll
        for (int s = 0; s < 4; ++s)
            bfrag[s] = *(const short8v*)&r2c[bc + s * 32];
    }
    // 32 MFMA per wave: 8 m-blocks x 4 k-steps, A streamed from L2
    const short8v* w3mf = (const short8v*)(ws + OFF_W3T);
    f32x4 acc[8];
    #pragma unroll
    for (int m = 0; m < 8; ++m) {
        f32x4 a = {0.f, 0.f, 0.f, 0.f};
        const int Mb = w * 8 + m;
        #pragma unroll
        for (int s = 0; s < 4; ++s) {
            short8v av = w3mf[(Mb * 4 + s) * 64 + l];
            a = __builtin_amdgcn_mfma_f32_16x16x32_bf16(av, bfrag[s], a, 0, 0, 0);
        }
        acc[m] = a;
    }
    // per-m: transpose D through wave-private LDS (in-order DS, barrier-free)
    for (int m = 0; m < 8; ++m) {
        #pragma unroll
        for (int r = 0; r < 4; ++r)
            dstg[w][(l >> 4) * 4 + r][l & 15] = acc[m][r];
        const int row = l & 15, cg = l >> 4;
        float4 d4 = *(const float4*)&dstg[w][row][cg * 4];
        float bv = b3[w * 128 + m * 16 + row];
        float v0 = d4.x + bv, v1 = d4.y + bv, v2 = d4.z + bv, v3 = d4.w + bv;
        float s4 = (v0 + v1) + (v2 + v3);
        float q4 = fmaf(v0, v0, fmaf(v1, v1, fmaf(v2, v2, v3 * v3)));
        float m4 = fmaxf(fmaxf(v0, v1), fmaxf(v2, v3));
        s4 += __shfl_xor(s4, 16); q4 += __shfl_xor(q4, 16); m4 = fmaxf(m4, __shfl_xor(m4, 16));
        s4 += __shfl_xor(s4, 32); q4 += __shfl_xor(q4, 32); m4 = fmaxf(m4, __shfl_xor(m4, 32));
        if (l < 16) {
            const size_t o6 = (size_t)tile * 1024 + w * 128 + m * 16 + l;
            psum[o6] = s4;  psq[o6] = q4;  pmax[o6] = m4;
        }
    }
}

// ---------------- K4': BN3 stats + max over n + output (passing) ----------------
__global__ __launch_bounds__(256) void k4_out(const float* __restrict__ g3,
                                              const float* __restrict__ be3,
                                              float* __restrict__ out,
                                              const float* __restrict__ ws) {
    __shared__ float lsum[256], lsq[256], lmax[256];
    const int t = threadIdx.x;
    const int c = blockIdx.x;
    const float* psum = ws + OFF_PSUM;
    const float* psq  = ws + OFF_PSQ;
    const float* pmax = ws + OFF_PMAX;
    lsum[t] = psum[(size_t)t * 1024 + c];
    lsq[t]  = psq [(size_t)t * 1024 + c];
    lmax[t] = pmax[(size_t)t * 1024 + c];
    __syncthreads();
    for (int s = 128; s > 0; s >>= 1) {
        if (t < s) { lsum[t] += lsum[t + s]; lsq[t] += lsq[t + s]; }
        __syncthreads();
    }
    float mean = lsum[0] * (1.f / CNT2);
    float var  = lsq[0] * (1.f / CNT2) - mean * mean;
    float rs   = rsqrtf(var + EPS_);
    float sc   = g3[c] * rs;
    float sh   = fmaf(-mean, sc, be3[c]);
    const int wv = t >> 6, l = t & 63;
    float v = lmax[wv * 64 + l];                    // tile = wv*64+l is batch wv
    #pragma unroll
    for (int off = 32; off > 0; off >>= 1) v = fmaxf(v, __shfl_xor(v, off));
    if (l == 0) out[wv * 1024 + c] = fmaf(v, sc, sh);
}

extern "C" void kernel_launch(void* const* d_in, const int* in_sizes, int n_in,
                              void* d_out, int out_size, void* d_ws, size_t ws_size,
                              hipStream_t stream) {
    const float* x   = (const float*)d_in[0];
    const float* ips = (const float*)d_in[1];
    const float* w1  = (const float*)d_in[2];
    const float* b1  = (const float*)d_in[3];
    const float* g1  = (const float*)d_in[4];
    const float* be1 = (const float*)d_in[5];
    const float* w2  = (const float*)d_in[6];
    const float* b2  = (const float*)d_in[7];
    const float* g2  = (const float*)d_in[8];
    const float* be2 = (const float*)d_in[9];
    const float* w3  = (const float*)d_in[10];
    const float* b3  = (const float*)d_in[11];
    const float* g3  = (const float*)d_in[12];
    const float* be3 = (const float*)d_in[13];
    float* out = (float*)d_out;
    float* ws  = (float*)d_ws;

    hipLaunchKernelGGL(k1_feat, dim3(1024), dim3(256), 0, stream, x, ips, w1, b1, ws);
    hipLaunchKernelGGL(k2_fc2,  dim3(256),  dim3(256), 0, stream, w1, b1, g1, be1, w2, b2, w3, ws);
    hipLaunchKernelGGL(k3_fc3,  dim3(256),  dim3(512), 0, stream, g2, be2, b3, ws);
    hipLaunchKernelGGL(k4_out,  dim3(1024), dim3(256), 0, stream, g3, be3, out, ws);
}

// Round 12
// 56.866 us; speedup vs baseline: 1.0983x; 1.0474x over previous
//
#include <hip/hip_runtime.h>
#include <math.h>

// Problem constants
#define B_   4
#define N_   1024
#define K_   520
#define C2   128
#define NK   (N_*K_)
#define NROWS (B_*N_)                 // 4096
#define CNT1  ((float)(B_*N_*K_))     // 2129920
#define CNT2  ((float)(B_*N_))        // 4096
#define EPS_  1e-5f

// Workspace layout (float offsets).
#define OFF_PART1   0                          // [1024][32] moment partials
#define OFF_PART2   32768                      // [256][256] BN2 partials
#define OFF_M1      98304                      // [4096][64]  max_k h1
#define OFF_H2      360448                     // [4096][128] h2 (pre-BN2), [col][o]
#define OFF_W3T     884736                     // w3 as bf16 MFMA A-fragments (256 KB)
#define OFF_PSUM    1015808                    // [256][1024] per-tile h3 sums
#define OFF_PSQ     1277952                    // [256][1024]
#define OFF_PMAX    1540096                    // [256][1024]

typedef __attribute__((ext_vector_type(8))) short short8v;   // 8 bf16 (4 VGPR)
typedef __attribute__((ext_vector_type(4))) float f32x4;     // MFMA acc
typedef __attribute__((ext_vector_type(2))) float f32x2;     // packed fp32 (VOP3P)

__device__ __forceinline__ unsigned f2bf(float f) {          // RNE fp32->bf16
    unsigned u = __float_as_uint(f);
    unsigned r = u + 0x7FFFu + ((u >> 16) & 1u);
    return r >> 16;
}

// ---------------- K1: conv1 (6->64) + max over K + 27 moment partials -----------
// 1024 blocks x 256 thr; wave wv owns row bid*4+wv.
// Lane-k ownership is now CONTIGUOUS QUADS: lane l holds k = {4l..4l+3,
// 256+4l..256+4l+3} via two float4 loads per input channel (row stride
// 2080 B = 130*16 -> 16B-aligned), + scalar tail k=512+l for l<8.
// 9 VMEM instrs/lane vs 27 scalar dwords. Max/moments are k-order-independent.
__global__ __launch_bounds__(256) void k1_feat(const float* __restrict__ x,
                                               const float* __restrict__ ips,
                                               const float* __restrict__ w1,
                                               const float* __restrict__ b1,
                                               float* __restrict__ ws) {
    __shared__ float base1s[4][64];
    __shared__ float lt[4][32][65];
    __shared__ float mom[4][28];
    float* m1    = ws + OFF_M1;
    float* part1 = ws + OFF_PART1;
    const int t = threadIdx.x;
    const int wv = t >> 6, lane = t & 63;
    const int row = blockIdx.x * 4 + wv;
    const int b = row >> 10, n = row & 1023;

    const float x0 = x[(b*3+0)*N_ + n];            // wave-uniform
    const float x1 = x[(b*3+1)*N_ + n];
    const float x2 = x[(b*3+2)*N_ + n];
    {   // base1 per channel (lane = c): per-lane loads, 3 fma, one LDS write
        const int c = lane;
        float wd0 = w1[c*6+3] - w1[c*6+0];
        float wd1 = w1[c*6+4] - w1[c*6+1];
        float wd2 = w1[c*6+5] - w1[c*6+2];
        base1s[wv][c] = fmaf(wd0, x0, fmaf(wd1, x1, fmaf(wd2, x2, b1[c])));
    }
    const size_t gb = ((size_t)(b*3)*N_ + n) * (size_t)K_;
    float a0[9], a1[9], a2[9];
    {   // two float4 loads per channel: k = 4*lane.. and 256+4*lane..
        float4 v;
        v = *(const float4*)(ips + gb        + 4*lane);
        a0[0]=v.x; a0[1]=v.y; a0[2]=v.z; a0[3]=v.w;
        v = *(const float4*)(ips + gb        + 256 + 4*lane);
        a0[4]=v.x; a0[5]=v.y; a0[6]=v.z; a0[7]=v.w;
        v = *(const float4*)(ips + gb +   NK + 4*lane);
        a1[0]=v.x; a1[1]=v.y; a1[2]=v.z; a1[3]=v.w;
        v = *(const float4*)(ips + gb +   NK + 256 + 4*lane);
        a1[4]=v.x; a1[5]=v.y; a1[6]=v.z; a1[7]=v.w;
        v = *(const float4*)(ips + gb + 2*NK + 4*lane);
        a2[0]=v.x; a2[1]=v.y; a2[2]=v.z; a2[3]=v.w;
        v = *(const float4*)(ips + gb + 2*NK + 256 + 4*lane);
        a2[4]=v.x; a2[5]=v.y; a2[6]=v.z; a2[7]=v.w;
    }
    const bool extra = (lane < 8);
    {
        int keo = extra ? (512 + lane) : lane;
        float v0 = ips[gb + keo], v1 = ips[gb + NK + keo], v2 = ips[gb + 2*NK + keo];
        a0[8] = extra ? v0 : 0.f;  a1[8] = extra ? v1 : 0.f;  a2[8] = extra ? v2 : 0.f;
    }
    // pack j=0..7 into f32x2 pairs for VOP3P
    f32x2 A0[4], A1[4], A2[4];
    #pragma unroll
    for (int p = 0; p < 4; ++p) {
        A0[p] = (f32x2){a0[2*p], a0[2*p+1]};
        A1[p] = (f32x2){a1[2*p], a1[2*p+1]};
        A2[p] = (f32x2){a2[2*p], a2[2*p+1]};
    }
    // per-channel max over K, two batches of 32 channels via LDS transpose.
    // lt[wv] is wave-private: DS ops are in-order per wave, no barriers needed.
    float m_out0 = 0.f, m_out1 = 0.f;
    #pragma unroll
    for (int cb = 0; cb < 2; ++cb) {
        #pragma unroll 8
        for (int ci = 0; ci < 32; ++ci) {
            const int c = cb*32 + ci;
            const float wc0 = w1[c*6+0];           // uniform -> scalar loads
            const float wc1 = w1[c*6+1];
            const float wc2 = w1[c*6+2];
            const float bs = base1s[wv][c];        // broadcast b32
            const f32x2 wx = {wc0, wc0}, wy = {wc1, wc1}, wz = {wc2, wc2};
            const f32x2 bs2 = {bs, bs};
            f32x2 vm2 = {-INFINITY, -INFINITY};
            #pragma unroll
            for (int p = 0; p < 4; ++p) {
                f32x2 h = wx*A0[p] + wy*A1[p] + wz*A2[p] + bs2;  // pk_fma chain
                vm2 = __builtin_elementwise_max(vm2, h);          // pk_max
            }
            float vm = fmaxf(vm2.x, vm2.y);
            float h8 = fmaf(wc0, a0[8], fmaf(wc1, a1[8], fmaf(wc2, a2[8], bs)));
            float vmE = fmaxf(vm, h8);
            vm = extra ? vmE : vm;                 // pad lanes exclude j=8
            lt[wv][ci][lane] = vm;                 // conflict-free write
        }
        const int ci = lane & 31, half = lane >> 5;
        float p = -INFINITY;
        #pragma unroll
        for (int j = 0; j < 32; ++j) p = fmaxf(p, lt[wv][ci][half*32 + j]);
        p = fmaxf(p, __shfl_xor(p, 32));
        if (cb == 0) m_out0 = p; else m_out1 = p;
    }
    if (lane < 32) {
        m1[(size_t)row*64 + lane]      = m_out0;
        m1[(size_t)row*64 + 32 + lane] = m_out1;
    }
    // moments from the same registers
    float mg0=0,mg1=0,mg2=0,mg3=0,mg4=0,mg5=0,s0=0,s1=0,s2=0;
    #pragma unroll
    for (int j = 0; j < 9; ++j) {
        float i0=a0[j], i1=a1[j], i2=a2[j];
        mg0=fmaf(i0,i0,mg0); mg1=fmaf(i0,i1,mg1); mg2=fmaf(i0,i2,mg2);
        mg3=fmaf(i1,i1,mg3); mg4=fmaf(i1,i2,mg4); mg5=fmaf(i2,i2,mg5);
        s0+=i0; s1+=i1; s2+=i2;
    }
    #pragma unroll
    for (int off=32; off>0; off>>=1) {
        mg0+=__shfl_xor(mg0,off); mg1+=__shfl_xor(mg1,off); mg2+=__shfl_xor(mg2,off);
        mg3+=__shfl_xor(mg3,off); mg4+=__shfl_xor(mg4,off); mg5+=__shfl_xor(mg5,off);
        s0 +=__shfl_xor(s0, off); s1 +=__shfl_xor(s1, off); s2 +=__shfl_xor(s2, off);
    }
    if (lane == 0) {
        float* mo = mom[wv];
        mo[0]=mg0; mo[1]=mg1; mo[2]=mg2; mo[3]=mg3; mo[4]=mg4; mo[5]=mg5;
        mo[6]=s0;  mo[7]=s1;  mo[8]=s2;
        mo[9] =s0*x0; mo[10]=s0*x1; mo[11]=s0*x2;
        mo[12]=s1*x0; mo[13]=s1*x1; mo[14]=s1*x2;
        mo[15]=s2*x0; mo[16]=s2*x1; mo[17]=s2*x2;
        mo[18]=x0*x0; mo[19]=x0*x1; mo[20]=x0*x2; mo[21]=x1*x1; mo[22]=x1*x2; mo[23]=x2*x2;
        mo[24]=x0; mo[25]=x1; mo[26]=x2;
    }
    __syncthreads();
    if (t < 32)   // zero-pad slots 27..31 so K2's float4 reduce is poison-free
        part1[blockIdx.x*32 + t] =
            (t < 27) ? (mom[0][t] + mom[1][t] + mom[2][t] + mom[3][t]) : 0.f;
}

// ---------------- K2': BN1 reduce + w3 bf16-fragment pack + FC2 + BN2 partials --
// 256 blocks x 256 thr, 16 cols each. r1 for ALL 16 columns staged once
// (r1all[16][65], one barrier) -> no barriers inside the FC2 loop.
__global__ __launch_bounds__(256) void k2_fc2(const float* __restrict__ w1,
                                              const float* __restrict__ b1,
                                              const float* __restrict__ g1,
                                              const float* __restrict__ be1,
                                              const float* __restrict__ w2,
                                              const float* __restrict__ b2,
                                              const float* __restrict__ w3,
                                              float* __restrict__ ws) {
    __shared__ float w2l[C2 * 65];
    __shared__ __align__(16) float red4[32][8][4];
    __shared__ float mo[32];
    __shared__ float sc1[64], sh1[64];
    __shared__ float r1all[16][65];
    __shared__ float lred[256];
    const int t = threadIdx.x;
    const int bid = blockIdx.x;
    const float* m1 = ws + OFF_M1;
    float* h2    = ws + OFF_H2;
    float* part2 = ws + OFF_PART2;
    if (bid < 64) {   // w3 -> bf16 A-fragments (16384 slots x 16B)
        const int slot = bid*256 + t;
        const int Mb = slot >> 8, s = (slot >> 6) & 3, l2 = slot & 63;
        const int row = l2 & 15, g = l2 >> 4;
        const float* src = w3 + (size_t)(Mb*16 + row)*128 + s*32 + g*8;
        float4 f0 = *(const float4*)src;
        float4 f1 = *(const float4*)(src + 4);
        uint4 u;
        u.x = f2bf(f0.x) | (f2bf(f0.y) << 16);
        u.y = f2bf(f0.z) | (f2bf(f0.w) << 16);
        u.z = f2bf(f1.x) | (f2bf(f1.y) << 16);
        u.w = f2bf(f1.z) | (f2bf(f1.w) << 16);
        ((uint4*)(ws + OFF_W3T))[slot] = u;
    }
    {   // BN1 moment reduce, coalesced float4 (deterministic fixed order)
        const float4* p14 = (const float4*)(ws + OFF_PART1);   // [1024][8] float4
        const int sg = t & 7, rr = t >> 3;
        float4 acc = {0.f, 0.f, 0.f, 0.f};
        #pragma unroll 4
        for (int it = 0; it < 32; ++it) {
            float4 v = p14[(size_t)(rr + 32*it)*8 + sg];
            acc.x += v.x; acc.y += v.y; acc.z += v.z; acc.w += v.w;
        }
        *(float4*)&red4[rr][sg][0] = acc;
    }
    for (int idx = t; idx < C2 * 64; idx += 256) {  // stage w2 (padded rows)
        int o = idx >> 6, i = idx & 63;
        w2l[o * 65 + i] = w2[idx];
    }
    __syncthreads();
    if (t < 32) {
        float m = 0.f;
        #pragma unroll
        for (int k = 0; k < 32; ++k) m += red4[k][t >> 2][t & 3];
        mo[t] = m;
    }
    __syncthreads();
    if (t < 64) {   // BN1 closed form (proven R4)
        const int c = t;
        float w0 = w1[c*6+0], w1v = w1[c*6+1], w2v = w1[c*6+2];
        float wd0 = w1[c*6+3]-w0, wd1 = w1[c*6+4]-w1v, wd2 = w1[c*6+5]-w2v;
        float bb = b1[c];
        float wcS = w0*mo[6] + w1v*mo[7] + w2v*mo[8];
        float wdX = wd0*mo[24] + wd1*mo[25] + wd2*mo[26];
        float ssum = wcS + 520.f*(wdX + 4096.f*bb);
        float t1 = w0*w0*mo[0] + w1v*w1v*mo[3] + w2v*w2v*mo[5]
                 + 2.f*(w0*w1v*mo[1] + w0*w2v*mo[2] + w1v*w2v*mo[4]);
        float Pt = w0 *(mo[9]*wd0  + mo[10]*wd1 + mo[11]*wd2)
                 + w1v*(mo[12]*wd0 + mo[13]*wd1 + mo[14]*wd2)
                 + w2v*(mo[15]*wd0 + mo[16]*wd1 + mo[17]*wd2);
        float t2 = 2.f*(Pt + bb*wcS);
        float Qt = wd0*wd0*mo[18] + wd1*wd1*mo[21] + wd2*wd2*mo[23]
                 + 2.f*(wd0*wd1*mo[19] + wd0*wd2*mo[20] + wd1*wd2*mo[22]);
        float t3 = 520.f*(Qt + 2.f*bb*wdX + 4096.f*bb*bb);
        float mean = ssum * (1.f / CNT1);
        float var  = (t1+t2+t3) * (1.f / CNT1) - mean*mean;
        float sc   = g1[c] * rsqrtf(var + EPS_);
        sc1[c] = sc;
        sh1[c] = fmaf(-mean, sc, be1[c]);
    }
    __syncthreads();
    {   // stage r1 for all 16 cols at once (coalesced reads, one barrier)
        #pragma unroll
        for (int m = 0; m < 4; ++m) {
            int idx = t + 256 * m;
            int col = idx >> 6, ci = idx & 63;
            float v = m1[(size_t)(bid * 16 + col) * 64 + ci];
            r1all[col][ci] = fmaxf(0.f, fmaf(v, sc1[ci], sh1[ci]));
        }
    }
    __syncthreads();
    const int o = t & 127, cg = t >> 7;
    const float bo = b2[o];
    float s2 = 0.f, q2 = 0.f;
    const int colbase = bid * 16;
    for (int it = 0; it < 8; ++it) {
        float acc = 0.f;
        const float* wr = w2l + o * 65;
        const float* rr = r1all[it * 2 + cg];
        #pragma unroll 8
        for (int i = 0; i < 64; ++i) acc = fmaf(wr[i], rr[i], acc);
        float h = acc + bo;
        h2[(size_t)(colbase + it * 2 + cg) * 128 + o] = h;   // [col][o], coalesced
        s2 += h;
        q2 = fmaf(h, h, q2);
    }
    __syncthreads();
    lred[t] = s2;
    __syncthreads();
    if (t < 128) part2[bid * 256 + t] = lred[t] + lred[128 + t];
    __syncthreads();
    lred[t] = q2;
    __syncthreads();
    if (t < 128) part2[bid * 256 + 128 + t] = lred[t] + lred[128 + t];
}

// ---------------- K3': BN2 reduce + FC3 via bf16 MFMA + h3 tile partials --------
// (R11, passing.) 256 blocks x 512 thr (8 waves). Tile = 16 cols of one b.
__global__ __launch_bounds__(512) void k3_fc3(const float* __restrict__ g2,
                                              const float* __restrict__ be2,
                                              const float* __restrict__ b3,
                                              float* __restrict__ ws) {
    __shared__ float tot2[2][256];
    __shared__ float sc2[128], sh2[128];
    __shared__ __align__(16) unsigned short r2c[16 * 136];   // bf16 B, padded rows
    __shared__ float dstg[8][16][20];                        // per-wave D transpose
    const int t = threadIdx.x;
    const int w = t >> 6, l = t & 63;
    const float* h2  = ws + OFF_H2;
    float* psum = ws + OFF_PSUM;
    float* psq  = ws + OFF_PSQ;
    float* pmax = ws + OFF_PMAX;
    const int tile = blockIdx.x;                    // 0..255
    const int b = tile >> 6, n0 = (tile & 63) * 16;
    {   // BN2 reduce (redundant per block; deterministic fixed order)
        const float* part2 = ws + OFF_PART2;
        const int c2 = t & 255, h = t >> 8;
        float acc = 0.f;
        for (int r = 0; r < 128; ++r) acc += part2[(h*128 + r)*256 + c2];
        tot2[h][c2] = acc;
    }
    __syncthreads();
    if (t < 128) {
        float s = tot2[0][t]       + tot2[1][t];
        float q = tot2[0][128 + t] + tot2[1][128 + t];
        float mean = s * (1.f / CNT2);
        float var  = q * (1.f / CNT2) - mean*mean;
        float sc   = g2[t] * rsqrtf(var + EPS_);
        sc2[t] = sc;
        sh2[t] = fmaf(-mean, sc, be2[t]);
    }
    __syncthreads();
    {   // stage r2 tile as bf16: r2c[col][k], col = n-index, k = input channel
        const int col = t >> 5, k0 = (t & 31) * 4;
        float4 v = *(const float4*)(h2 + (size_t)(b * N_ + n0 + col) * 128 + k0);
        float r0 = fmaxf(0.f, fmaf(v.x, sc2[k0+0], sh2[k0+0]));
        float r1 = fmaxf(0.f, fmaf(v.y, sc2[k0+1], sh2[k0+1]));
        float r2 = fmaxf(0.f, fmaf(v.z, sc2[k0+2], sh2[k0+2]));
        float r3 = fmaxf(0.f, fmaf(v.w, sc2[k0+3], sh2[k0+3]));
        unsigned u0 = f2bf(r0) | (f2bf(r1) << 16);
        unsigned u1 = f2bf(r2) | (f2bf(r3) << 16);
        *(uint2*)&r2c[col * 136 + k0] = make_uint2(u0, u1);
    }
    __syncthreads();
    // B fragments: lane l -> col = l&15, k = s*32 + (l>>4)*8 + j
    short8v bfrag[4];
    {
        const int bc = (l & 15) * 136 + (l >> 4) * 8;
        #pragma unroll
        for (int s = 0; s < 4; ++s)
            bfrag[s] = *(const short8v*)&r2c[bc + s * 32];
    }
    // 32 MFMA per wave: 8 m-blocks x 4 k-steps, A streamed from L2
    const short8v* w3mf = (const short8v*)(ws + OFF_W3T);
    f32x4 acc[8];
    #pragma unroll
    for (int m = 0; m < 8; ++m) {
        f32x4 a = {0.f, 0.f, 0.f, 0.f};
        const int Mb = w * 8 + m;
        #pragma unroll
        for (int s = 0; s < 4; ++s) {
            short8v av = w3mf[(Mb * 4 + s) * 64 + l];
            a = __builtin_amdgcn_mfma_f32_16x16x32_bf16(av, bfrag[s], a, 0, 0, 0);
        }
        acc[m] = a;
    }
    // per-m: transpose D through wave-private LDS (in-order DS, barrier-free)
    for (int m = 0; m < 8; ++m) {
        #pragma unroll
        for (int r = 0; r < 4; ++r)
            dstg[w][(l >> 4) * 4 + r][l & 15] = acc[m][r];
        const int row = l & 15, cg = l >> 4;
        float4 d4 = *(const float4*)&dstg[w][row][cg * 4];
        float bv = b3[w * 128 + m * 16 + row];
        float v0 = d4.x + bv, v1 = d4.y + bv, v2 = d4.z + bv, v3 = d4.w + bv;
        float s4 = (v0 + v1) + (v2 + v3);
        float q4 = fmaf(v0, v0, fmaf(v1, v1, fmaf(v2, v2, v3 * v3)));
        float m4 = fmaxf(fmaxf(v0, v1), fmaxf(v2, v3));
        s4 += __shfl_xor(s4, 16); q4 += __shfl_xor(q4, 16); m4 = fmaxf(m4, __shfl_xor(m4, 16));
        s4 += __shfl_xor(s4, 32); q4 += __shfl_xor(q4, 32); m4 = fmaxf(m4, __shfl_xor(m4, 32));
        if (l < 16) {
            const size_t o6 = (size_t)tile * 1024 + w * 128 + m * 16 + l;
            psum[o6] = s4;  psq[o6] = q4;  pmax[o6] = m4;
        }
    }
}

// ---------------- K4': BN3 stats + max over n + output (passing) ----------------
__global__ __launch_bounds__(256) void k4_out(const float* __restrict__ g3,
                                              const float* __restrict__ be3,
                                              float* __restrict__ out,
                                              const float* __restrict__ ws) {
    __shared__ float lsum[256], lsq[256], lmax[256];
    const int t = threadIdx.x;
    const int c = blockIdx.x;
    const float* psum = ws + OFF_PSUM;
    const float* psq  = ws + OFF_PSQ;
    const float* pmax = ws + OFF_PMAX;
    lsum[t] = psum[(size_t)t * 1024 + c];
    lsq[t]  = psq [(size_t)t * 1024 + c];
    lmax[t] = pmax[(size_t)t * 1024 + c];
    __syncthreads();
    for (int s = 128; s > 0; s >>= 1) {
        if (t < s) { lsum[t] += lsum[t + s]; lsq[t] += lsq[t + s]; }
        __syncthreads();
    }
    float mean = lsum[0] * (1.f / CNT2);
    float var  = lsq[0] * (1.f / CNT2) - mean * mean;
    float rs   = rsqrtf(var + EPS_);
    float sc   = g3[c] * rs;
    float sh   = fmaf(-mean, sc, be3[c]);
    const int wv = t >> 6, l = t & 63;
    float v = lmax[wv * 64 + l];                    // tile = wv*64+l is batch wv
    #pragma unroll
    for (int off = 32; off > 0; off >>= 1) v = fmaxf(v, __shfl_xor(v, off));
    if (l == 0) out[wv * 1024 + c] = fmaf(v, sc, sh);
}

extern "C" void kernel_launch(void* const* d_in, const int* in_sizes, int n_in,
                              void* d_out, int out_size, void* d_ws, size_t ws_size,
                              hipStream_t stream) {
    const float* x   = (const float*)d_in[0];
    const float* ips = (const float*)d_in[1];
    const float* w1  = (const float*)d_in[2];
    const float* b1  = (const float*)d_in[3];
    const float* g1  = (const float*)d_in[4];
    const float* be1 = (const float*)d_in[5];
    const float* w2  = (const float*)d_in[6];
    const float* b2  = (const float*)d_in[7];
    const float* g2  = (const float*)d_in[8];
    const float* be2 = (const float*)d_in[9];
    const float* w3  = (const float*)d_in[10];
    const float* b3  = (const float*)d_in[11];
    const float* g3  = (const float*)d_in[12];
    const float* be3 = (const float*)d_in[13];
    float* out = (float*)d_out;
    float* ws  = (float*)d_ws;

    hipLaunchKernelGGL(k1_feat, dim3(1024), dim3(256), 0, stream, x, ips, w1, b1, ws);
    hipLaunchKernelGGL(k2_fc2,  dim3(256),  dim3(256), 0, stream, w1, b1, g1, be1, w2, b2, w3, ws);
    hipLaunchKernelGGL(k3_fc3,  dim3(256),  dim3(512), 0, stream, g2, be2, b3, ws);
    hipLaunchKernelGGL(k4_out,  dim3(1024), dim3(256), 0, stream, g3, be3, out, ws);
}